// Round 3
// baseline (562.922 us; speedup 1.0000x reference)
//
#include <hip/hip_runtime.h>
#include <stdint.h>

#define IN_DIM 8192
#define OUT_DIM 4096
#define NNZ 1638400
#define BATCH 4096

typedef __bf16 bf16x8 __attribute__((ext_vector_type(8)));
typedef float f32x4 __attribute__((ext_vector_type(4)));
typedef short s16x2 __attribute__((ext_vector_type(2)));

// ---- helpers ----------------------------------------------------------------

__device__ __forceinline__ unsigned short f2bf(float f) {
  union { float f; unsigned int u; } v; v.f = f;
  unsigned int u = v.u;
  unsigned int r = (u + 0x7FFFu + ((u >> 16) & 1u)) >> 16;  // RNE
  return (unsigned short)r;
}

__device__ __forceinline__ void async16(const void* g, void* l) {
  __builtin_amdgcn_global_load_lds(
      (const __attribute__((address_space(1))) unsigned int*)g,
      (__attribute__((address_space(3))) unsigned int*)l,
      16, 0, 0);
}

__device__ __forceinline__ void convert_body(int i, const float* __restrict__ src,
                                             unsigned short* __restrict__ dst) {
  const float4* s = (const float4*)src;
  float4 a = s[2 * i];
  float4 b = s[2 * i + 1];
  union { unsigned short us[8]; uint4 v; } o;
  o.us[0] = f2bf(a.x); o.us[1] = f2bf(a.y); o.us[2] = f2bf(a.z); o.us[3] = f2bf(a.w);
  o.us[4] = f2bf(b.x); o.us[5] = f2bf(b.y); o.us[6] = f2bf(b.z); o.us[7] = f2bf(b.w);
  ((uint4*)dst)[i] = o.v;
}

// ---- kernel 1: zero W_bf16 --------------------------------------------------

#define ZERO_BLOCKS ((IN_DIM * OUT_DIM) / 8 / 256)  // 16384

__global__ void zero_kernel(uint4* __restrict__ W) {
  W[blockIdx.x * 256 + threadIdx.x] = make_uint4(0, 0, 0, 0);
}

// ---- kernel 2: fused x-convert + scatter ------------------------------------

#if defined(__has_builtin)
#  if __has_builtin(__builtin_amdgcn_global_atomic_fadd_v2bf16)
#    define HAVE_PK_BF16 1
#  endif
#endif

__device__ __forceinline__ void scat1(int c, int r, float w,
                                      unsigned int* __restrict__ W) {
  size_t e = (size_t)c * IN_DIM + r;     // element index in W^T [OUT][IN]
  const bool hi = (e & 1);
  unsigned short nb = f2bf(w);
#ifdef HAVE_PK_BF16
  s16x2 v;
  v.x = hi ? (short)0 : (short)nb;
  v.y = hi ? (short)nb : (short)0;
  __builtin_amdgcn_global_atomic_fadd_v2bf16(
      (__attribute__((address_space(1))) s16x2*)(W + (e >> 1)), v);
#else
  unsigned int* p = W + (e >> 1);
  unsigned int nw0 = hi ? ((unsigned int)nb << 16) : (unsigned int)nb;
  unsigned int cur = atomicCAS(p, 0u, nw0);
  if (cur == 0u) return;
  unsigned int assumed;
  do {
    assumed = cur;
    unsigned short h = hi ? (unsigned short)(assumed >> 16)
                          : (unsigned short)(assumed & 0xFFFFu);
    union { unsigned int u; float f; } hv; hv.u = (unsigned int)h << 16;
    unsigned short b2 = f2bf(hv.f + w);
    unsigned int nw = hi ? ((assumed & 0x0000FFFFu) | ((unsigned int)b2 << 16))
                         : ((assumed & 0xFFFF0000u) | (unsigned int)b2);
    cur = atomicCAS(p, assumed, nw);
  } while (cur != assumed);
#endif
}

__global__ void conv_scat_kernel(const float* __restrict__ x,
                                 unsigned short* __restrict__ x_bf16,
                                 const int4* __restrict__ ri4,
                                 const int4* __restrict__ ci4,
                                 const float4* __restrict__ w4,
                                 unsigned int* __restrict__ W) {
  int i = blockIdx.x * 256 + threadIdx.x;
  convert_body(i, x, x_bf16);
  if (i < NNZ / 4) {
    int4 r = ri4[i];
    int4 c = ci4[i];
    float4 w = w4[i];
    scat1(c.x, r.x, w.x, W);
    scat1(c.y, r.y, w.y, W);
    scat1(c.z, r.z, w.z, W);
    scat1(c.w, r.w, w.w, W);
  }
}

// ---- kernel 3: bf16 GEMM, 256x256 tile, 8 waves, burst prefetch -------------
// C[M,N] = A[M,K] * Bt[N,K]^T + bias. R1 schedule (48% MfmaUtil, proven) with
// ONE change: all 8 next-tile global_load_lds issue in a burst at phase 0
// (into the dead buffer) instead of spread across phases. Every drained load
// is then a full K-tile (~2000 cyc) old -> vmcnt(8) drain is ~free. The
// overwrite of the dead buffer is safe: q3's post-MFMA barrier guarantees all
// waves' ds_reads of it completed (lgkmcnt precedes MFMA issue precedes
// barrier arrival) before any wave issues the stores.

#define TBM 256
#define TBN 256
#define TBK 64
#define NKT (IN_DIM / TBK)  // 128

__global__ __launch_bounds__(512, 2) void gemm_kernel(
    const unsigned short* __restrict__ A,   // [BATCH][IN_DIM] bf16 bits
    const unsigned short* __restrict__ Bt,  // [OUT_DIM][IN_DIM] bf16 bits
    const float* __restrict__ bias,         // [OUT_DIM]
    float* __restrict__ C) {                // [BATCH][OUT_DIM] fp32
  extern __shared__ __align__(16) unsigned short lds[];  // 131072 B

  const int tid = threadIdx.x;

  // bijective XCD swizzle: 256 workgroups, 8 XCDs, 32 each.
  const int bid = blockIdx.x;
  const int swz = ((bid & 7) << 5) | (bid >> 3);
  const int m0 = (swz & 15) * TBM;   // m fastest within XCD -> B-panel L2 reuse
  const int n0 = (swz >> 4) * TBN;

  const int wid = tid >> 6;
  const int lane = tid & 63;
  const int wm = wid >> 2;       // 0..1
  const int wn = wid & 3;        // 0..3
  const int quad = lane >> 4;
  const int lm = lane & 15;
  const int xorv = lm & 7;

  const unsigned short* Ab = A + (size_t)m0 * IN_DIM;
  const unsigned short* Bb = Bt + (size_t)n0 * IN_DIM;

  // staging geometry: tile = 256 rows x 8 segs of 16B; 512 thr -> 4 rounds.
  int soff[4], ldst[4];
#pragma unroll
  for (int c = 0; c < 4; ++c) {
    const int t2 = c * 512 + tid;
    const int srow = t2 >> 3;
    const int sgs = (t2 & 7) ^ (srow & 7);    // stage-side swizzle
    soff[c] = srow * IN_DIM + sgs * 8;
    ldst[c] = t2 * 16;                         // LDS byte offset (linear dest)
  }

  f32x4 acc[8][4] = {};

#define STAGE(kt_, b_, c_)                                                  \
  do {                                                                      \
    const int k0_ = (kt_)*TBK;                                              \
    char* la_ = (char*)lds + (b_)*65536;                                    \
    async16(Ab + (size_t)soff[c_] + k0_, la_ + ldst[c_]);                   \
    async16(Bb + (size_t)soff[c_] + k0_, la_ + 32768 + ldst[c_]);           \
  } while (0)

  // prologue: stage K-tile 0 fully into buf 0 (8 loads/thread)
#pragma unroll
  for (int c = 0; c < 4; ++c) STAGE(0, 0, c);

  for (int kt = 0; kt < NKT; ++kt) {
    const int buf = kt & 1;
    const int nbuf = buf ^ 1;
    const int ktn = (kt + 1) & (NKT - 1);  // wraps at end: dummy reload, drained post-loop

    // burst-stage tile kt+1 into dead buffer, then drain THIS tile's 8 loads.
#pragma unroll
    for (int c = 0; c < 4; ++c) STAGE(ktn, nbuf, c);
    asm volatile("s_waitcnt vmcnt(8)" ::: "memory");
    __builtin_amdgcn_sched_barrier(0);
    __builtin_amdgcn_s_barrier();          // all waves: buf[buf] complete

    const unsigned short* lA = lds + buf * 32768;  // elements (64 KiB/buf)
    const unsigned short* lB = lA + 16384;

    // B fragments for the whole K-tile (8 x ds_read_b128, held in regs)
    bf16x8 bfr[4][2];
#pragma unroll
    for (int j = 0; j < 4; ++j) {
      const int row = wn * 64 + j * 16 + lm;
#pragma unroll
      for (int ss = 0; ss < 2; ++ss) {
        const int p = ((ss << 2) | quad) ^ xorv;   // read-side inverse swizzle
        bfr[j][ss] = *(const bf16x8*)(lB + row * TBK + p * 8);
      }
    }

#pragma unroll
    for (int q = 0; q < 4; ++q) {
      bf16x8 af[2][2];
#pragma unroll
      for (int i = 0; i < 2; ++i) {
        const int row = wm * 128 + (q * 2 + i) * 16 + lm;
#pragma unroll
        for (int ss = 0; ss < 2; ++ss) {
          const int p = ((ss << 2) | quad) ^ xorv;
          af[i][ss] = *(const bf16x8*)(lA + row * TBK + p * 8);
        }
      }
      __builtin_amdgcn_s_barrier();
      __builtin_amdgcn_s_setprio(1);
#pragma unroll
      for (int i = 0; i < 2; ++i)
#pragma unroll
        for (int j = 0; j < 4; ++j)
#pragma unroll
          for (int ss = 0; ss < 2; ++ss)
            acc[q * 2 + i][j] = __builtin_amdgcn_mfma_f32_16x16x32_bf16(
                af[i][ss], bfr[j][ss], acc[q * 2 + i][j], 0, 0, 0);
      __builtin_amdgcn_s_setprio(0);
      __builtin_amdgcn_s_barrier();
    }
  }
#undef STAGE

  // retire the dummy tail loads before LDS deallocation / endpgm.
  asm volatile("s_waitcnt vmcnt(0)" ::: "memory");

  // Epilogue: C/D layout col = lane&15, row = quad*4 + reg  [m89-verified]
  const int ccol0 = n0 + wn * 64 + lm;
  const int crow0 = m0 + wm * 128;
#pragma unroll
  for (int j = 0; j < 4; ++j) {
    const int col = ccol0 + j * 16;
    const float bv = bias[col];
#pragma unroll
    for (int i = 0; i < 8; ++i) {
#pragma unroll
      for (int v = 0; v < 4; ++v) {
        const int row = crow0 + i * 16 + quad * 4 + v;
        C[(size_t)row * OUT_DIM + col] = acc[i][j][v] + bv;
      }
    }
  }
}

// ---- launch -----------------------------------------------------------------

extern "C" void kernel_launch(void* const* d_in, const int* in_sizes, int n_in,
                              void* d_out, int out_size, void* d_ws, size_t ws_size,
                              hipStream_t stream) {
  const float* x = (const float*)d_in[0];       // [4096][8192] fp32
  const int* row_idx = (const int*)d_in[1];     // [NNZ] int32
  const int* col_idx = (const int*)d_in[2];     // [NNZ] int32
  const float* weights = (const float*)d_in[3]; // [NNZ] fp32
  const float* bias = (const float*)d_in[4];    // [4096] fp32
  float* out = (float*)d_out;                   // [4096][4096] fp32

  // ws layout: W_bf16 [0,64M), x_bf16 [64M,128M).
  const size_t W_BF16_BYTES = (size_t)IN_DIM * OUT_DIM * 2;  // 64 MiB
  unsigned short* W_bf16 = (unsigned short*)d_ws;
  unsigned short* x_bf16 = (unsigned short*)((char*)d_ws + W_BF16_BYTES);

  static bool attr_set = false;
  if (!attr_set) {
    (void)hipFuncSetAttribute((const void*)gemm_kernel,
                              hipFuncAttributeMaxDynamicSharedMemorySize,
                              131072);
    attr_set = true;
  }

  // 1. zero W_bf16
  zero_kernel<<<ZERO_BLOCKS, 256, 0, stream>>>((uint4*)W_bf16);

  // 2. fused x->bf16 convert + scatter-add (atomics hide under stream)
  conv_scat_kernel<<<ZERO_BLOCKS, 256, 0, stream>>>(
      x, x_bf16, (const int4*)row_idx, (const int4*)col_idx,
      (const float4*)weights, (unsigned int*)W_bf16);

  // 3. GEMM + bias (256^2 tile, 8 waves, XCD-swizzled 1-D grid of 256)
  gemm_kernel<<<dim3(256), dim3(512), 131072, stream>>>(x_bf16, W_bf16, bias, out);
}

// Round 4
// 510.381 us; speedup vs baseline: 1.1029x; 1.1029x over previous
//
#include <hip/hip_runtime.h>
#include <stdint.h>

#define IN_DIM 8192
#define OUT_DIM 4096
#define NNZ 1638400
#define BATCH 4096

typedef __bf16 bf16x8 __attribute__((ext_vector_type(8)));
typedef float f32x4 __attribute__((ext_vector_type(4)));

// ---- helpers ----------------------------------------------------------------

__device__ __forceinline__ unsigned short f2bf(float f) {
  union { float f; unsigned int u; } v; v.f = f;
  unsigned int u = v.u;
  unsigned int r = (u + 0x7FFFu + ((u >> 16) & 1u)) >> 16;  // RNE
  return (unsigned short)r;
}

__device__ __forceinline__ float bf2f(unsigned short b) {
  union { unsigned int u; float f; } v;
  v.u = (unsigned int)b << 16;
  return v.f;
}

__device__ __forceinline__ void async16(const void* g, void* l) {
  __builtin_amdgcn_global_load_lds(
      (const __attribute__((address_space(1))) unsigned int*)g,
      (__attribute__((address_space(3))) unsigned int*)l,
      16, 0, 0);
}

__device__ __forceinline__ void convert_body(int i, const float* __restrict__ src,
                                             unsigned short* __restrict__ dst) {
  const float4* s = (const float4*)src;
  float4 a = s[2 * i];
  float4 b = s[2 * i + 1];
  union { unsigned short us[8]; uint4 v; } o;
  o.us[0] = f2bf(a.x); o.us[1] = f2bf(a.y); o.us[2] = f2bf(a.z); o.us[3] = f2bf(a.w);
  o.us[4] = f2bf(b.x); o.us[5] = f2bf(b.y); o.us[6] = f2bf(b.z); o.us[7] = f2bf(b.w);
  ((uint4*)dst)[i] = o.v;
}

// ---- kernel 1: zero W_bf16 + convert x, perfectly uniform pairing -----------
// (R0 structure restored: measured-best non-GEMM half, 253 us residual.)

#define PREP_BLOCKS ((IN_DIM * OUT_DIM) / 8 / 256)  // 16384

__global__ void prep_kernel(uint4* __restrict__ W_zero,
                            const float* __restrict__ x,
                            unsigned short* __restrict__ x_bf16) {
  int i = blockIdx.x * 256 + threadIdx.x;
  W_zero[i] = make_uint4(0, 0, 0, 0);
  convert_body(i, x, x_bf16);
}

// ---- kernel 2: scatter-add into bf16 W via 32-bit CAS (R0 verbatim) ---------

__device__ __forceinline__ void scat1(int c, int r, float w,
                                      unsigned int* __restrict__ W) {
  size_t e = (size_t)c * IN_DIM + r;     // element index in W^T [OUT][IN]
  unsigned int* p = W + (e >> 1);
  const bool hi = (e & 1);
  unsigned int cur = *p;                 // seed (CAS corrects staleness)
  unsigned int assumed;
  do {
    assumed = cur;
    unsigned short h = hi ? (unsigned short)(assumed >> 16)
                          : (unsigned short)(assumed & 0xFFFFu);
    unsigned short nb = f2bf(bf2f(h) + w);
    unsigned int nw = hi ? ((assumed & 0x0000FFFFu) | ((unsigned int)nb << 16))
                         : ((assumed & 0xFFFF0000u) | (unsigned int)nb);
    cur = atomicCAS(p, assumed, nw);
  } while (cur != assumed);
}

#define SCAT_BLOCKS (NNZ / 4 / 256)  // 1600

__global__ void scatter_kernel(const int4* __restrict__ ri4,
                               const int4* __restrict__ ci4,
                               const float4* __restrict__ w4,
                               unsigned int* __restrict__ W) {
  int i = blockIdx.x * 256 + threadIdx.x;
  int4 r = ri4[i];
  int4 c = ci4[i];
  float4 w = w4[i];
  scat1(c.x, r.x, w.x, W);
  scat1(c.y, r.y, w.y, W);
  scat1(c.z, r.z, w.z, W);
  scat1(c.w, r.w, w.w, W);
}

// ---- kernel 3: bf16 GEMM, 256x256 tile, 8 waves, BARRIER-LIGHT --------------
// C[M,N] = A[M,K] * Bt[N,K]^T + bias.
// One barrier + one (near-free) vmcnt(0) per K-tile; no intra-tile phase
// barriers. Correctness:
//  (a) vmcnt(0) BEFORE the barrier: each wave confirms its own tile-kt loads
//      landed; barrier then makes them visible to all waves. The drained
//      loads were issued one full K-tile earlier (~4000 cyc) -> wait ~free.
//  (b) staging of nbuf AFTER the barrier: every wave's reads of nbuf (tile
//      kt-1 data) were consumed by its MFMAs (implicit lgkmcnt) before it
//      arrived at this barrier -> overwrite is safe.
// Waves run the 24 ds_read + 64 MFMA tile body unsynchronized: compiler's
// fine-grained lgkmcnt pipelines reads under MFMAs in-wave; desynced waves
// co-schedule MFMA vs LDS pipes across the SIMD (m114); setprio favors the
// MFMA-cluster wave.

#define TBM 256
#define TBN 256
#define TBK 64
#define NKT (IN_DIM / TBK)  // 128

__global__ __launch_bounds__(512, 2) void gemm_kernel(
    const unsigned short* __restrict__ A,   // [BATCH][IN_DIM] bf16 bits
    const unsigned short* __restrict__ Bt,  // [OUT_DIM][IN_DIM] bf16 bits
    const float* __restrict__ bias,         // [OUT_DIM]
    float* __restrict__ C) {                // [BATCH][OUT_DIM] fp32
  extern __shared__ __align__(16) unsigned short lds[];  // 131072 B

  const int tid = threadIdx.x;

  // bijective XCD swizzle: 256 workgroups, 8 XCDs, 32 each.
  const int bid = blockIdx.x;
  const int swz = ((bid & 7) << 5) | (bid >> 3);
  const int m0 = (swz & 15) * TBM;   // m fastest within XCD -> B-panel L2 reuse
  const int n0 = (swz >> 4) * TBN;

  const int wid = tid >> 6;
  const int lane = tid & 63;
  const int wm = wid >> 2;       // 0..1
  const int wn = wid & 3;        // 0..3
  const int quad = lane >> 4;
  const int lm = lane & 15;
  const int xorv = lm & 7;

  const unsigned short* Ab = A + (size_t)m0 * IN_DIM;
  const unsigned short* Bb = Bt + (size_t)n0 * IN_DIM;

  // staging geometry: tile = 256 rows x 8 segs of 16B; 512 thr -> 4 rounds.
  int soff[4], ldst[4];
#pragma unroll
  for (int c = 0; c < 4; ++c) {
    const int t2 = c * 512 + tid;
    const int srow = t2 >> 3;
    const int sgs = (t2 & 7) ^ (srow & 7);    // stage-side swizzle
    soff[c] = srow * IN_DIM + sgs * 8;
    ldst[c] = t2 * 16;                         // LDS byte offset (linear dest)
  }

  f32x4 acc[8][4] = {};

#define STAGE(kt_, b_, c_)                                                  \
  do {                                                                      \
    const int k0_ = (kt_)*TBK;                                              \
    char* la_ = (char*)lds + (b_)*65536;                                    \
    async16(Ab + (size_t)soff[c_] + k0_, la_ + ldst[c_]);                   \
    async16(Bb + (size_t)soff[c_] + k0_, la_ + 32768 + ldst[c_]);           \
  } while (0)

  // prologue: stage K-tile 0 fully into buf 0 (8 loads/thread)
#pragma unroll
  for (int c = 0; c < 4; ++c) STAGE(0, 0, c);

  for (int kt = 0; kt < NKT; ++kt) {
    const int buf = kt & 1;
    const int nbuf = buf ^ 1;
    const int ktn = (kt + 1) & (NKT - 1);  // wraps at end: dummy reload

    // (a) own loads of THIS tile drained (aged one full tile -> ~free)...
    asm volatile("s_waitcnt vmcnt(0)" ::: "memory");
    __builtin_amdgcn_sched_barrier(0);
    // ...then cross-wave visibility + nbuf-read completion fence.
    __builtin_amdgcn_s_barrier();
    __builtin_amdgcn_sched_barrier(0);

    // (b) burst-stage tile kt+1 into the (now provably dead) buffer; these
    // fly under the whole tile body.
#pragma unroll
    for (int c = 0; c < 4; ++c) STAGE(ktn, nbuf, c);

    const unsigned short* lA = lds + buf * 32768;  // elements (64 KiB/buf)
    const unsigned short* lB = lA + 16384;

    // B fragments for the whole K-tile (8 x ds_read_b128, held in regs)
    bf16x8 bfr[4][2];
#pragma unroll
    for (int j = 0; j < 4; ++j) {
      const int row = wn * 64 + j * 16 + lm;
#pragma unroll
      for (int ss = 0; ss < 2; ++ss) {
        const int p = ((ss << 2) | quad) ^ xorv;   // read-side inverse swizzle
        bfr[j][ss] = *(const bf16x8*)(lB + row * TBK + p * 8);
      }
    }

#pragma unroll
    for (int q = 0; q < 4; ++q) {
      bf16x8 af[2][2];
#pragma unroll
      for (int i = 0; i < 2; ++i) {
        const int row = wm * 128 + (q * 2 + i) * 16 + lm;
#pragma unroll
        for (int ss = 0; ss < 2; ++ss) {
          const int p = ((ss << 2) | quad) ^ xorv;
          af[i][ss] = *(const bf16x8*)(lA + row * TBK + p * 8);
        }
      }
      __builtin_amdgcn_s_setprio(1);
#pragma unroll
      for (int i = 0; i < 2; ++i)
#pragma unroll
        for (int j = 0; j < 4; ++j)
#pragma unroll
          for (int ss = 0; ss < 2; ++ss)
            acc[q * 2 + i][j] = __builtin_amdgcn_mfma_f32_16x16x32_bf16(
                af[i][ss], bfr[j][ss], acc[q * 2 + i][j], 0, 0, 0);
      __builtin_amdgcn_s_setprio(0);
    }
  }
#undef STAGE

  // retire the dummy tail loads before LDS deallocation / endpgm.
  asm volatile("s_waitcnt vmcnt(0)" ::: "memory");

  // Epilogue: C/D layout col = lane&15, row = quad*4 + reg  [m89-verified]
  const int ccol0 = n0 + wn * 64 + lm;
  const int crow0 = m0 + wm * 128;
#pragma unroll
  for (int j = 0; j < 4; ++j) {
    const int col = ccol0 + j * 16;
    const float bv = bias[col];
#pragma unroll
    for (int i = 0; i < 8; ++i) {
#pragma unroll
      for (int v = 0; v < 4; ++v) {
        const int row = crow0 + i * 16 + quad * 4 + v;
        C[(size_t)row * OUT_DIM + col] = acc[i][j][v] + bv;
      }
    }
  }
}

// ---- launch -----------------------------------------------------------------

extern "C" void kernel_launch(void* const* d_in, const int* in_sizes, int n_in,
                              void* d_out, int out_size, void* d_ws, size_t ws_size,
                              hipStream_t stream) {
  const float* x = (const float*)d_in[0];       // [4096][8192] fp32
  const int* row_idx = (const int*)d_in[1];     // [NNZ] int32
  const int* col_idx = (const int*)d_in[2];     // [NNZ] int32
  const float* weights = (const float*)d_in[3]; // [NNZ] fp32
  const float* bias = (const float*)d_in[4];    // [4096] fp32
  float* out = (float*)d_out;                   // [4096][4096] fp32

  // ws layout: W_bf16 [0,64M), x_bf16 [64M,128M).
  const size_t W_BF16_BYTES = (size_t)IN_DIM * OUT_DIM * 2;  // 64 MiB
  unsigned short* W_bf16 = (unsigned short*)d_ws;
  unsigned short* x_bf16 = (unsigned short*)((char*)d_ws + W_BF16_BYTES);

  static bool attr_set = false;
  if (!attr_set) {
    (void)hipFuncSetAttribute((const void*)gemm_kernel,
                              hipFuncAttributeMaxDynamicSharedMemorySize,
                              131072);
    attr_set = true;
  }

  // 1. zero W_bf16 + convert x -> bf16 (uniform per-thread pairing)
  prep_kernel<<<PREP_BLOCKS, 256, 0, stream>>>((uint4*)W_bf16, x, x_bf16);

  // 2. scatter-add weights directly into bf16 W^T (CAS)
  scatter_kernel<<<SCAT_BLOCKS, 256, 0, stream>>>(
      (const int4*)row_idx, (const int4*)col_idx, (const float4*)weights,
      (unsigned int*)W_bf16);

  // 3. GEMM + bias (256^2 tile, 8 waves, XCD-swizzled 1-D grid of 256)
  gemm_kernel<<<dim3(256), dim3(512), 131072, stream>>>(x_bf16, W_bf16, bias, out);
}

// Round 5
// 506.584 us; speedup vs baseline: 1.1112x; 1.0075x over previous
//
#include <hip/hip_runtime.h>
#include <stdint.h>

#define IN_DIM 8192
#define OUT_DIM 4096
#define NNZ 1638400
#define BATCH 4096

typedef __bf16 bf16x8 __attribute__((ext_vector_type(8)));
typedef float f32x4 __attribute__((ext_vector_type(4)));

// ---- helpers ----------------------------------------------------------------

__device__ __forceinline__ unsigned short f2bf(float f) {
  union { float f; unsigned int u; } v; v.f = f;
  unsigned int u = v.u;
  unsigned int r = (u + 0x7FFFu + ((u >> 16) & 1u)) >> 16;  // RNE
  return (unsigned short)r;
}

__device__ __forceinline__ float bf2f(unsigned short b) {
  union { unsigned int u; float f; } v;
  v.u = (unsigned int)b << 16;
  return v.f;
}

__device__ __forceinline__ void async16(const void* g, void* l) {
  __builtin_amdgcn_global_load_lds(
      (const __attribute__((address_space(1))) unsigned int*)g,
      (__attribute__((address_space(3))) unsigned int*)l,
      16, 0, 0);
}

__device__ __forceinline__ void convert_body(int i, const float* __restrict__ src,
                                             unsigned short* __restrict__ dst) {
  const float4* s = (const float4*)src;
  float4 a = s[2 * i];
  float4 b = s[2 * i + 1];
  union { unsigned short us[8]; uint4 v; } o;
  o.us[0] = f2bf(a.x); o.us[1] = f2bf(a.y); o.us[2] = f2bf(a.z); o.us[3] = f2bf(a.w);
  o.us[4] = f2bf(b.x); o.us[5] = f2bf(b.y); o.us[6] = f2bf(b.z); o.us[7] = f2bf(b.w);
  ((uint4*)dst)[i] = o.v;
}

// ---- kernel 1: zero W_bf16 + convert x (unchanged since R0) -----------------

#define PREP_BLOCKS ((IN_DIM * OUT_DIM) / 8 / 256)  // 16384

__global__ void prep_kernel(uint4* __restrict__ W_zero,
                            const float* __restrict__ x,
                            unsigned short* __restrict__ x_bf16) {
  int i = blockIdx.x * 256 + threadIdx.x;
  W_zero[i] = make_uint4(0, 0, 0, 0);
  convert_body(i, x, x_bf16);
}

// ---- kernel 2: scatter-add into bf16 W via 32-bit CAS (unchanged) -----------

__device__ __forceinline__ void scat1(int c, int r, float w,
                                      unsigned int* __restrict__ W) {
  size_t e = (size_t)c * IN_DIM + r;     // element index in W^T [OUT][IN]
  unsigned int* p = W + (e >> 1);
  const bool hi = (e & 1);
  unsigned int cur = *p;                 // seed (CAS corrects staleness)
  unsigned int assumed;
  do {
    assumed = cur;
    unsigned short h = hi ? (unsigned short)(assumed >> 16)
                          : (unsigned short)(assumed & 0xFFFFu);
    unsigned short nb = f2bf(bf2f(h) + w);
    unsigned int nw = hi ? ((assumed & 0x0000FFFFu) | ((unsigned int)nb << 16))
                         : ((assumed & 0xFFFF0000u) | (unsigned int)nb);
    cur = atomicCAS(p, assumed, nw);
  } while (cur != assumed);
}

#define SCAT_BLOCKS (NNZ / 4 / 256)  // 1600

__global__ void scatter_kernel(const int4* __restrict__ ri4,
                               const int4* __restrict__ ci4,
                               const float4* __restrict__ w4,
                               unsigned int* __restrict__ W) {
  int i = blockIdx.x * 256 + threadIdx.x;
  int4 r = ri4[i];
  int4 c = ci4[i];
  float4 w = w4[i];
  scat1(c.x, r.x, w.x, W);
  scat1(c.y, r.y, w.y, W);
  scat1(c.z, r.z, w.z, W);
  scat1(c.w, r.w, w.w, W);
}

// ---- kernel 3: bf16 GEMM, 256x256 tile, 8 waves, barrier-light --------------
// R4 schedule (proven: 1211 TF, MfmaUtil 52%) with ONE change: XCD->tile
// mapping rebalanced from 16m x 2n to 8m x 4n regions per XCD.
// HW dispatch puts block bid on XCD (bid&7); j = bid>>3 indexes 32 blocks
// within the XCD. Old: m=j&15, n=2*xcd+(j>>4) -> per-XCD unique = 16 A-panels
// + 2 B-panels = 72 MB. New: m=(xcd&1)*8+(j&7), n=(xcd>>1)*4+(j>>3) ->
// 8 A-panels + 4 B-panels = 48 MB (-33% L2-fill demand). Bijective:
// (xcd,j) <-> (m,n) by construction.

#define TBM 256
#define TBN 256
#define TBK 64
#define NKT (IN_DIM / TBK)  // 128

__global__ __launch_bounds__(512, 2) void gemm_kernel(
    const unsigned short* __restrict__ A,   // [BATCH][IN_DIM] bf16 bits
    const unsigned short* __restrict__ Bt,  // [OUT_DIM][IN_DIM] bf16 bits
    const float* __restrict__ bias,         // [OUT_DIM]
    float* __restrict__ C) {                // [BATCH][OUT_DIM] fp32
  extern __shared__ __align__(16) unsigned short lds[];  // 131072 B

  const int tid = threadIdx.x;

  // XCD-region swizzle: 8m x 4n block region per XCD.
  const int bid = blockIdx.x;
  const int xcd = bid & 7;
  const int j = bid >> 3;
  const int m0 = ((xcd & 1) * 8 + (j & 7)) * TBM;
  const int n0 = ((xcd >> 1) * 4 + (j >> 3)) * TBN;

  const int wid = tid >> 6;
  const int lane = tid & 63;
  const int wm = wid >> 2;       // 0..1
  const int wn = wid & 3;        // 0..3
  const int quad = lane >> 4;
  const int lm = lane & 15;
  const int xorv = lm & 7;

  const unsigned short* Ab = A + (size_t)m0 * IN_DIM;
  const unsigned short* Bb = Bt + (size_t)n0 * IN_DIM;

  // staging geometry: tile = 256 rows x 8 segs of 16B; 512 thr -> 4 rounds.
  int soff[4], ldst[4];
#pragma unroll
  for (int c = 0; c < 4; ++c) {
    const int t2 = c * 512 + tid;
    const int srow = t2 >> 3;
    const int sgs = (t2 & 7) ^ (srow & 7);    // stage-side swizzle
    soff[c] = srow * IN_DIM + sgs * 8;
    ldst[c] = t2 * 16;                         // LDS byte offset (linear dest)
  }

  f32x4 acc[8][4] = {};

#define STAGE(kt_, b_, c_)                                                  \
  do {                                                                      \
    const int k0_ = (kt_)*TBK;                                              \
    char* la_ = (char*)lds + (b_)*65536;                                    \
    async16(Ab + (size_t)soff[c_] + k0_, la_ + ldst[c_]);                   \
    async16(Bb + (size_t)soff[c_] + k0_, la_ + 32768 + ldst[c_]);           \
  } while (0)

  // prologue: stage K-tile 0 fully into buf 0 (8 loads/thread)
#pragma unroll
  for (int c = 0; c < 4; ++c) STAGE(0, 0, c);

  for (int kt = 0; kt < NKT; ++kt) {
    const int buf = kt & 1;
    const int nbuf = buf ^ 1;
    const int ktn = (kt + 1) & (NKT - 1);  // wraps at end: dummy reload

    // (a) own loads of THIS tile drained (aged one full tile)...
    asm volatile("s_waitcnt vmcnt(0)" ::: "memory");
    __builtin_amdgcn_sched_barrier(0);
    // ...then cross-wave visibility + nbuf-read completion fence.
    __builtin_amdgcn_s_barrier();
    __builtin_amdgcn_sched_barrier(0);

    // (b) burst-stage tile kt+1 into the (now provably dead) buffer.
#pragma unroll
    for (int c = 0; c < 4; ++c) STAGE(ktn, nbuf, c);

    const unsigned short* lA = lds + buf * 32768;  // elements (64 KiB/buf)
    const unsigned short* lB = lA + 16384;

    // B fragments for the whole K-tile (8 x ds_read_b128, held in regs)
    bf16x8 bfr[4][2];
#pragma unroll
    for (int j2 = 0; j2 < 4; ++j2) {
      const int row = wn * 64 + j2 * 16 + lm;
#pragma unroll
      for (int ss = 0; ss < 2; ++ss) {
        const int p = ((ss << 2) | quad) ^ xorv;   // read-side inverse swizzle
        bfr[j2][ss] = *(const bf16x8*)(lB + row * TBK + p * 8);
      }
    }

#pragma unroll
    for (int q = 0; q < 4; ++q) {
      bf16x8 af[2][2];
#pragma unroll
      for (int i = 0; i < 2; ++i) {
        const int row = wm * 128 + (q * 2 + i) * 16 + lm;
#pragma unroll
        for (int ss = 0; ss < 2; ++ss) {
          const int p = ((ss << 2) | quad) ^ xorv;
          af[i][ss] = *(const bf16x8*)(lA + row * TBK + p * 8);
        }
      }
      __builtin_amdgcn_s_setprio(1);
#pragma unroll
      for (int i = 0; i < 2; ++i)
#pragma unroll
        for (int j2 = 0; j2 < 4; ++j2)
#pragma unroll
          for (int ss = 0; ss < 2; ++ss)
            acc[q * 2 + i][j2] = __builtin_amdgcn_mfma_f32_16x16x32_bf16(
                af[i][ss], bfr[j2][ss], acc[q * 2 + i][j2], 0, 0, 0);
      __builtin_amdgcn_s_setprio(0);
    }
  }
#undef STAGE

  // retire the dummy tail loads before LDS deallocation / endpgm.
  asm volatile("s_waitcnt vmcnt(0)" ::: "memory");

  // Epilogue: C/D layout col = lane&15, row = quad*4 + reg  [m89-verified]
  const int ccol0 = n0 + wn * 64 + lm;
  const int crow0 = m0 + wm * 128;
#pragma unroll
  for (int j2 = 0; j2 < 4; ++j2) {
    const int col = ccol0 + j2 * 16;
    const float bv = bias[col];
#pragma unroll
    for (int i = 0; i < 8; ++i) {
#pragma unroll
      for (int v = 0; v < 4; ++v) {
        const int row = crow0 + i * 16 + quad * 4 + v;
        C[(size_t)row * OUT_DIM + col] = acc[i][j2][v] + bv;
      }
    }
  }
}

// ---- launch -----------------------------------------------------------------

extern "C" void kernel_launch(void* const* d_in, const int* in_sizes, int n_in,
                              void* d_out, int out_size, void* d_ws, size_t ws_size,
                              hipStream_t stream) {
  const float* x = (const float*)d_in[0];       // [4096][8192] fp32
  const int* row_idx = (const int*)d_in[1];     // [NNZ] int32
  const int* col_idx = (const int*)d_in[2];     // [NNZ] int32
  const float* weights = (const float*)d_in[3]; // [NNZ] fp32
  const float* bias = (const float*)d_in[4];    // [4096] fp32
  float* out = (float*)d_out;                   // [4096][4096] fp32

  // ws layout: W_bf16 [0,64M), x_bf16 [64M,128M).
  const size_t W_BF16_BYTES = (size_t)IN_DIM * OUT_DIM * 2;  // 64 MiB
  unsigned short* W_bf16 = (unsigned short*)d_ws;
  unsigned short* x_bf16 = (unsigned short*)((char*)d_ws + W_BF16_BYTES);

  static bool attr_set = false;
  if (!attr_set) {
    (void)hipFuncSetAttribute((const void*)gemm_kernel,
                              hipFuncAttributeMaxDynamicSharedMemorySize,
                              131072);
    attr_set = true;
  }

  // 1. zero W_bf16 + convert x -> bf16
  prep_kernel<<<PREP_BLOCKS, 256, 0, stream>>>((uint4*)W_bf16, x, x_bf16);

  // 2. scatter-add weights directly into bf16 W^T (CAS)
  scatter_kernel<<<SCAT_BLOCKS, 256, 0, stream>>>(
      (const int4*)row_idx, (const int4*)col_idx, (const float4*)weights,
      (unsigned int*)W_bf16);

  // 3. GEMM + bias (256^2 tile, 8 waves, XCD-region-swizzled grid of 256)
  gemm_kernel<<<dim3(256), dim3(512), 131072, stream>>>(x_bf16, W_bf16, bias, out);
}